// Round 3
// baseline (57.940 us; speedup 1.0000x reference)
//
#include <hip/hip_runtime.h>
#include <math.h>

#define M_CB 8
#define K_CB 1024
#define D_CB 128
#define HW   1024
#define NB   4
#define HALF_LOG_2PI 0.9189385332046727f
#define EPS_S 1e-5f
#define LOG2E 1.4426950408889634f
#define LN2   0.6931471805599453f
#define DEFER_THR 12.0f

typedef float f32x4 __attribute__((ext_vector_type(4)));
typedef short s16x8 __attribute__((ext_vector_type(8)));

__device__ __forceinline__ void gl2lds16(const void* g, void* l) {
    __builtin_amdgcn_global_load_lds(
        (const __attribute__((address_space(1))) void*)g,
        (__attribute__((address_space(3))) void*)l, 16, 0, 0);
}

__device__ __forceinline__ short f2bf(float f) {   // RNE fp32 -> bf16 bits
    unsigned u = __builtin_bit_cast(unsigned, f);
    u += 0x7fffu + ((u >> 16) & 1u);
    return (short)(u >> 16);
}

// ws float offsets
#define WS_PART  16                      // 512 partials
#define WS_A     1024                    // A2l  [8][1024]
#define WS_C0    (WS_A + 8192)           // c0l  [8][1024]
#define WS_ST    (WS_C0 + 8192)          // states 6 x [2][8][4096]
#define WS_MU_F  (WS_ST + 6 * 65536)     // bf16 mus, 2 MB

// ------------- kernel 1: mus -> bf16 (swizzled) + per-k constants (log2 domain) --
// thread t: db = t&15 (16B dest block), k = (t>>4)&1023, m = t>>14
__global__ __launch_bounds__(256) void vq_convert(
    const float* __restrict__ mus, const float* __restrict__ scales,
    const float* __restrict__ logpy, ushort* __restrict__ wmu,
    float* __restrict__ A2l, float* __restrict__ c0l)
{
    const int t  = blockIdx.x * 256 + threadIdx.x;
    const int db = t & 15;
    const int k  = (t >> 4) & (K_CB - 1);
    const int m  = t >> 14;
    const float* row = mus + ((size_t)m * K_CB + k) * D_CB;
    const int d0 = 8 * (db ^ (k & 7));          // swizzle involution on 16B blocks
    const float4 v0 = *reinterpret_cast<const float4*>(row + d0);
    const float4 v1 = *reinterpret_cast<const float4*>(row + d0 + 4);
    s16x8 o;
    o[0] = f2bf(v0.x); o[1] = f2bf(v0.y); o[2] = f2bf(v0.z); o[3] = f2bf(v0.w);
    o[4] = f2bf(v1.x); o[5] = f2bf(v1.y); o[6] = f2bf(v1.z); o[7] = f2bf(v1.w);
    *reinterpret_cast<s16x8*>(wmu + ((size_t)(m * K_CB + k) * D_CB + db * 8)) = o;

    float ssq = v0.x*v0.x + v0.y*v0.y + v0.z*v0.z + v0.w*v0.w
              + v1.x*v1.x + v1.y*v1.y + v1.z*v1.z + v1.w*v1.w;
    #pragma unroll
    for (int o2 = 8; o2 >= 1; o2 >>= 1) ssq += __shfl_xor(ssq, o2, 64);
    if (db == 0) {
        const float s = fmaxf(scales[m * K_CB + k], EPS_S);
        const float A = 0.5f / (s * s);
        const float lpy = logpy[m * K_CB + k];
        A2l[m * K_CB + k] = 2.f * A * LOG2E;
        c0l[m * K_CB + k] = (fmaf(-(float)D_CB, logf(s) + HALF_LOG_2PI, lpy) - A * ssq) * LOG2E;
    }
}

// ------------- kernel 2: fused MFMA dist + deferred-max softmax/KL/argmax -------
// grid (128, 8): blockIdx.x = bx*2 + kz (64 px-tiles x 2 k-halves), y = m
// LDS: [0,32K) mu double-buffer 2x16KB; [32K,38K) consts A2l/c0l/logpy (512 k each)
__global__ __launch_bounds__(256, 4) void vq_main(
    const float* __restrict__ x, const ushort* __restrict__ wmu,
    const float* __restrict__ A2l, const float* __restrict__ c0l,
    const float* __restrict__ logpy, float* __restrict__ st)
{
    __shared__ __align__(16) unsigned char arena[32768 + 6144];
    float* As = (float*)(arena + 32768);
    float* Cs = As + 512;
    float* Ps = Cs + 512;

    const int tid = threadIdx.x;
    const int w   = tid >> 6;      // wave 0..3
    const int l   = tid & 63;
    const int g   = l >> 4;        // k-subset within wave
    const int n   = l & 15;        // pixel within wave
    const int bx2 = blockIdx.x;
    const int bx  = bx2 >> 1;      // pixel tile 0..63
    const int kz  = bx2 & 1;       // k half
    const int m   = blockIdx.y;
    const int bimg = bx >> 4;
    const int hw0  = (bx & 15) * 64;
    const size_t xbase = (size_t)bimg * (M_CB * D_CB * HW) + (size_t)m * (D_CB * HW) + hw0;

    // ---- stage per-k consts (3 x 2KB for this block's 512 k) ----
    if (w < 3) {
        const float* carr = (w == 0 ? A2l : w == 1 ? c0l : logpy) + m * K_CB + kz * 512;
        gl2lds16((const char*)carr + l * 16,        arena + 32768 + w * 2048);
        gl2lds16((const char*)carr + 1024 + l * 16, arena + 32768 + w * 2048 + 1024);
    }

    // ---- x fragments + ||x||^2 straight from global (no LDS round-trip) ----
    const float* xpx = x + xbase + w * 16 + n;
    float xs = 0.f;
    s16x8 xf[4];
    #pragma unroll
    for (int c = 0; c < 4; ++c) {
        #pragma unroll
        for (int j = 0; j < 8; ++j) {
            const float v = xpx[(size_t)(c * 32 + g * 8 + j) * HW];
            xs = fmaf(v, v, xs);
            xf[c][j] = f2bf(v);
        }
    }
    xs += __shfl_xor(xs, 16, 64);
    xs += __shfl_xor(xs, 32, 64);
    const float xsh = 0.5f * xs;

    // ---- deferred-max state (log2 domain), per-lane k-subset ----
    float M2 = -1e30f, S = 0.f, U2 = 0.f, V = 0.f, BL = -1e30f;
    int BI = 0;

    const char* mubase = (const char*)wmu + ((size_t)m * K_CB + kz * 512) * (D_CB * 2);
    #pragma unroll
    for (int r = 0; r < 4; ++r)
        gl2lds16(mubase + r * 4096 + w * 1024 + l * 16, arena + r * 4096 + w * 1024);
    __syncthreads();

    for (int c = 0; c < 8; ++c) {
        const int buf = c & 1;
        if (c < 7) {
            const char* src = mubase + (size_t)(c + 1) * 16384;
            #pragma unroll
            for (int r = 0; r < 4; ++r)
                gl2lds16(src + r * 4096 + w * 1024 + l * 16,
                         arena + (buf ^ 1) * 16384 + r * 4096 + w * 1024);
        }
        const unsigned bb = buf * 16384;
        #pragma unroll
        for (int t = 0; t < 4; ++t) {
            f32x4 acc = {0.f, 0.f, 0.f, 0.f};
            const int row = t * 16 + n;
            const unsigned rbase = bb + row * 256;
            const unsigned sw = (unsigned)((row & 7) << 4);
            #pragma unroll
            for (int dc = 0; dc < 4; ++dc) {
                const s16x8 a = *(const s16x8*)(arena + rbase + (((unsigned)(dc * 64 + g * 16)) ^ sw));
                acc = __builtin_amdgcn_mfma_f32_16x16x32_bf16(a, xf[dc], acc, 0, 0, 0);
            }
            const int k0 = c * 64 + t * 16 + g * 4;    // local k (0..511)
            const f32x4 A4 = *(const f32x4*)(As + k0);
            const f32x4 C4 = *(const f32x4*)(Cs + k0);
            const f32x4 P4 = *(const f32x4*)(Ps + k0);
            #pragma unroll
            for (int r = 0; r < 4; ++r) {
                const float L2 = fmaf(A4[r], acc[r], fmaf(-A4[r], xsh, C4[r]));
                const float diff = L2 - M2;
                if (__builtin_expect(__any(diff > DEFER_THR), 0)) {
                    if (diff > DEFER_THR) {            // rescale to new reference
                        const float sc = exp2f(-diff);
                        U2 = (U2 - diff * S) * sc;
                        S  = fmaf(S, sc, 1.f);
                        V  = fmaf(V, sc, P4[r]);
                        M2 = L2;
                    } else {
                        const float e = exp2f(diff);
                        S += e; U2 = fmaf(e, diff, U2); V = fmaf(e, P4[r], V);
                    }
                } else {                               // common path: ~9 VALU
                    const float e = exp2f(diff);
                    S += e; U2 = fmaf(e, diff, U2); V = fmaf(e, P4[r], V);
                }
                if (L2 > BL) { BL = L2; BI = k0 + r; }
            }
        }
        __syncthreads();
    }

    // ---- butterfly merge of the 4 k-subsets (lanes differ in g) ----
    #pragma unroll
    for (int off = 16; off <= 32; off <<= 1) {
        const float Mb  = __shfl_xor(M2, off, 64);
        const float Sb  = __shfl_xor(S,  off, 64);
        const float Ub  = __shfl_xor(U2, off, 64);
        const float Vb  = __shfl_xor(V,  off, 64);
        const float BLb = __shfl_xor(BL, off, 64);
        const int   BIb = __shfl_xor(BI, off, 64);
        const float Mc = fmaxf(M2, Mb);
        const float sa = exp2f(M2 - Mc), sb = exp2f(Mb - Mc);
        const float Sn = S * sa + Sb * sb;
        U2 = fmaf(M2 - Mc, S, U2) * sa + fmaf(Mb - Mc, Sb, Ub) * sb;
        V  = V * sa + Vb * sb;
        S  = Sn; M2 = Mc;
        const bool tb = (BLb > BL) || (BLb == BL && BIb < BI);
        BI = tb ? BIb : BI;
        BL = fmaxf(BL, BLb);
    }

    if (l < 16) {
        const int idx = (kz * M_CB + m) * 4096 + bx * 64 + w * 16 + n;
        st[0 * 65536 + idx] = M2;
        st[1 * 65536 + idx] = S;
        st[2 * 65536 + idx] = U2;
        st[3 * 65536 + idx] = V;
        st[4 * 65536 + idx] = BL;
        ((int*)st)[5 * 65536 + idx] = kz * 512 + BI;
    }
}

// ------------- kernel 3: merge k-halves -> kl partial + sample write ------------
__global__ __launch_bounds__(256) void vq_merge(
    const float* __restrict__ mus, const float* __restrict__ st,
    float* __restrict__ out, float* __restrict__ partial)
{
    __shared__ float smp[64][129];
    __shared__ int idxs[64];
    const int tid = threadIdx.x, bx = blockIdx.x, m = blockIdx.y;

    if (tid < 64) {
        const int ia = (0 * M_CB + m) * 4096 + bx * 64 + tid;
        const int ib = (1 * M_CB + m) * 4096 + bx * 64 + tid;
        const float Ma = st[ia],           Mb = st[ib];
        const float Sa = st[65536 + ia],   Sb = st[65536 + ib];
        const float Ua = st[131072 + ia],  Ub = st[131072 + ib];
        const float Va = st[196608 + ia],  Vb = st[196608 + ib];
        const float BLa = st[262144 + ia], BLb = st[262144 + ib];
        const int BIa = ((const int*)st)[327680 + ia];
        const int BIb = ((const int*)st)[327680 + ib];

        const float Mc = fmaxf(Ma, Mb);
        const float sa = exp2f(Ma - Mc), sb = exp2f(Mb - Mc);
        const float Sx = Sa * sa + Sb * sb;
        const float Ux = fmaf(Ma - Mc, Sa, Ua) * sa + fmaf(Mb - Mc, Sb, Ub) * sb;
        const float Vx = Va * sa + Vb * sb;
        const bool tb = (BLb > BLa) || (BLb == BLa && BIb < BIa);
        idxs[tid] = tb ? BIb : BIa;
        // kl with V accumulated against RAW log_py; +lse[m] correction in finalize
        float kl = (LN2 * Ux - Vx) / Sx - logf(Sx);
        #pragma unroll
        for (int o = 32; o >= 1; o >>= 1) kl += __shfl_xor(kl, o, 64);
        if (tid == 0) partial[m * 64 + bx] = kl;
    }
    __syncthreads();

    // gather chosen mu rows coalesced -> LDS (transpose buffer)
    const int w = tid >> 6, l = tid & 63;
    #pragma unroll
    for (int i = 0; i < 8; ++i) {
        const int p = w * 16 + i * 2 + (l >> 5);
        const int c = l & 31;
        const float4 v = *reinterpret_cast<const float4*>(
            mus + ((size_t)m * K_CB + idxs[p]) * D_CB + c * 4);
        smp[p][c * 4 + 0] = v.x; smp[p][c * 4 + 1] = v.y;
        smp[p][c * 4 + 2] = v.z; smp[p][c * 4 + 3] = v.w;
    }
    __syncthreads();

    // coalesced store: 64 consecutive pixels per instruction
    const int p = tid & 63, d0 = tid >> 6;
    const size_t xbase = (size_t)(bx >> 4) * (M_CB * D_CB * HW) + (size_t)m * (D_CB * HW) + (bx & 15) * 64;
    #pragma unroll 8
    for (int dd = d0; dd < D_CB; dd += 4)
        out[xbase + (size_t)dd * HW + p] = smp[p][dd];
}

// ------------- kernel 4: lse correction + final KL reduce ----------------------
__global__ __launch_bounds__(256) void vq_final(const float* __restrict__ logpy,
                                                const float* __restrict__ partial,
                                                float* __restrict__ out)
{
    __shared__ float wred[4];
    const int tid = threadIdx.x;

    float lsesum = 0.f;
    for (int m = 0; m < M_CB; ++m) {
        const float4 v = reinterpret_cast<const float4*>(logpy + (size_t)m * K_CB)[tid];
        float mx = fmaxf(fmaxf(v.x, v.y), fmaxf(v.z, v.w));
        #pragma unroll
        for (int o = 32; o >= 1; o >>= 1) mx = fmaxf(mx, __shfl_xor(mx, o, 64));
        if ((tid & 63) == 0) wred[tid >> 6] = mx;
        __syncthreads();
        mx = fmaxf(fmaxf(wred[0], wred[1]), fmaxf(wred[2], wred[3]));
        __syncthreads();
        float e = expf(v.x - mx) + expf(v.y - mx) + expf(v.z - mx) + expf(v.w - mx);
        #pragma unroll
        for (int o = 32; o >= 1; o >>= 1) e += __shfl_xor(e, o, 64);
        if ((tid & 63) == 0) wred[tid >> 6] = e;
        __syncthreads();
        lsesum += mx + logf(wred[0] + wred[1] + wred[2] + wred[3]);
        __syncthreads();
    }

    float v = partial[tid] + partial[tid + 256];
    #pragma unroll
    for (int o = 32; o >= 1; o >>= 1) v += __shfl_xor(v, o, 64);
    if ((tid & 63) == 0) wred[tid >> 6] = v;
    __syncthreads();
    if (tid == 0) {
        const float ksum = wred[0] + wred[1] + wred[2] + wred[3];
        out[(size_t)NB * M_CB * D_CB * HW]     = (ksum + 4096.f * lsesum) * 0.25f;
        out[(size_t)NB * M_CB * D_CB * HW + 1] = 0.f;
    }
}

extern "C" void kernel_launch(void* const* d_in, const int* in_sizes, int n_in,
                              void* d_out, int out_size, void* d_ws, size_t ws_size,
                              hipStream_t stream)
{
    const float* x      = (const float*)d_in[0];
    const float* mus    = (const float*)d_in[1];
    const float* scales = (const float*)d_in[2];
    const float* logpy  = (const float*)d_in[3];
    float* out = (float*)d_out;
    float* ws  = (float*)d_ws;

    float*  partial = ws + WS_PART;
    float*  A2l     = ws + WS_A;
    float*  c0l     = ws + WS_C0;
    float*  st      = ws + WS_ST;
    ushort* wmu     = (ushort*)(ws + WS_MU_F);

    vq_convert<<<512,          256, 0, stream>>>(mus, scales, logpy, wmu, A2l, c0l);
    vq_main   <<<dim3(128, 8), 256, 0, stream>>>(x, wmu, A2l, c0l, logpy, st);
    vq_merge  <<<dim3(64, 8),  256, 0, stream>>>(mus, st, out, partial);
    vq_final  <<<1,            256, 0, stream>>>(logpy, partial, out);
}

// Round 4
// 51.419 us; speedup vs baseline: 1.1268x; 1.1268x over previous
//
#include <hip/hip_runtime.h>
#include <math.h>

#define M_CB 8
#define K_CB 1024
#define D_CB 128
#define HW   1024
#define NB   4
#define HALF_LOG_2PI 0.9189385332046727f
#define EPS_S 1e-5f
#define LOG2E 1.4426950408889634f
#define LN2   0.6931471805599453f
#define DEFER_THR 12.0f

typedef float f32x4 __attribute__((ext_vector_type(4)));
typedef short s16x8 __attribute__((ext_vector_type(8)));

__device__ __forceinline__ void gl2lds16(const void* g, void* l) {
    __builtin_amdgcn_global_load_lds(
        (const __attribute__((address_space(1))) void*)g,
        (__attribute__((address_space(3))) void*)l, 16, 0, 0);
}

__device__ __forceinline__ short f2bf(float f) {   // RNE fp32 -> bf16 bits
    unsigned u = __builtin_bit_cast(unsigned, f);
    u += 0x7fffu + ((u >> 16) & 1u);
    return (short)(u >> 16);
}

// ws float offsets
#define WS_PART  16                      // 1024 partials
#define WS_A     2048                    // A2l [8][1024]
#define WS_C0    (WS_A + 8192)           // c0l [8][1024]
#define WS_MU_F  (WS_C0 + 8192)          // frag-major bf16 mus, 2 MB

// ---- kernel 1: mus -> bf16 FRAG-MAJOR + per-k constants (log2 domain) ----------
// thread t: db = t&15 (8-d block), k = (t>>4)&1023, m = t>>14
// dest frag idx: (m*64 + kt)*256 + dc*64 + lane ; kt=k>>4, dc=db>>2, lane=(db&3)*16+(k&15)
__global__ __launch_bounds__(256) void vq_convert(
    const float* __restrict__ mus, const float* __restrict__ scales,
    const float* __restrict__ logpy, ushort* __restrict__ wmu,
    float* __restrict__ A2l, float* __restrict__ c0l)
{
    const int t  = blockIdx.x * 256 + threadIdx.x;
    const int db = t & 15;
    const int k  = (t >> 4) & (K_CB - 1);
    const int m  = t >> 14;
    const float* row = mus + ((size_t)m * K_CB + k) * D_CB;
    const float4 v0 = *reinterpret_cast<const float4*>(row + db * 8);
    const float4 v1 = *reinterpret_cast<const float4*>(row + db * 8 + 4);
    s16x8 o;
    o[0] = f2bf(v0.x); o[1] = f2bf(v0.y); o[2] = f2bf(v0.z); o[3] = f2bf(v0.w);
    o[4] = f2bf(v1.x); o[5] = f2bf(v1.y); o[6] = f2bf(v1.z); o[7] = f2bf(v1.w);
    const int kt = k >> 4, dc = db >> 2, lane = (db & 3) * 16 + (k & 15);
    reinterpret_cast<s16x8*>(wmu)[(size_t)(m * 64 + kt) * 256 + dc * 64 + lane] = o;

    float ssq = v0.x*v0.x + v0.y*v0.y + v0.z*v0.z + v0.w*v0.w
              + v1.x*v1.x + v1.y*v1.y + v1.z*v1.z + v1.w*v1.w;
    #pragma unroll
    for (int o2 = 8; o2 >= 1; o2 >>= 1) ssq += __shfl_xor(ssq, o2, 64);
    if (db == 0) {
        const float s = fmaxf(scales[m * K_CB + k], EPS_S);
        const float A = 0.5f / (s * s);
        const float lpy = logpy[m * K_CB + k];
        A2l[m * K_CB + k] = 2.f * A * LOG2E;
        c0l[m * K_CB + k] = (fmaf(-(float)D_CB, logf(s) + HALF_LOG_2PI, lpy) - A * ssq) * LOG2E;
    }
}

// ---- kernel 2: barrier-free MFMA dist + deferred softmax/KL/argmax + sample ----
// grid (128, 8): 128 tiles of 32 px, m. Block: 4 waves = {2 px-groups} x {2 k-halves}.
__global__ __launch_bounds__(256, 4) void vq_main(
    const float* __restrict__ x, const ushort* __restrict__ wmu,
    const float* __restrict__ mus, const float* __restrict__ A2l,
    const float* __restrict__ c0l, const float* __restrict__ logpy,
    float* __restrict__ out, float* __restrict__ partial)
{
    __shared__ __align__(16) float As[1024];
    __shared__ __align__(16) float Cs[1024];
    __shared__ __align__(16) float Ps[1024];
    __shared__ float smp[32][129];
    __shared__ float scrM[2][16], scrS[2][16], scrU[2][16], scrV[2][16], scrBL[2][16];
    __shared__ int   scrBI[2][16], sidx[32];
    __shared__ float wscr[2];

    const int tid = threadIdx.x;
    const int w   = tid >> 6;           // wave 0..3
    const int l   = tid & 63;
    const int g   = l >> 4;             // k-subset in wave
    const int n   = l & 15;             // pixel in wave's 16-px group
    const int khalf = w >> 1;           // waves 0,1 -> k<512 ; waves 2,3 -> k>=512
    const int pxg   = w & 1;            // pixel group 0/1
    const int tile = blockIdx.x;        // 0..127
    const int m    = blockIdx.y;
    const int img  = tile >> 5;
    const int hw0  = (tile & 31) * 32;
    const size_t xbase = (size_t)img * (M_CB * D_CB * HW) + (size_t)m * (D_CB * HW) + hw0;

    // ---- stage full per-k consts (3 x 4KB) ----
    gl2lds16((const char*)(A2l  + m * K_CB) + tid * 16, (char*)As + tid * 16);
    gl2lds16((const char*)(c0l  + m * K_CB) + tid * 16, (char*)Cs + tid * 16);
    gl2lds16((const char*)(logpy + m * K_CB) + tid * 16, (char*)Ps + tid * 16);

    // ---- x fragments + ||x||^2 straight from global ----
    const float* xpx = x + xbase + pxg * 16 + n;
    float xs = 0.f;
    s16x8 xf[4];
    #pragma unroll
    for (int c = 0; c < 4; ++c) {
        #pragma unroll
        for (int j = 0; j < 8; ++j) {
            const float v = xpx[(size_t)(c * 32 + g * 8 + j) * HW];
            xs = fmaf(v, v, xs);
            xf[c][j] = f2bf(v);
        }
    }
    xs += __shfl_xor(xs, 16, 64);
    xs += __shfl_xor(xs, 32, 64);
    const float xsh = 0.5f * xs;
    __syncthreads();                     // consts staged

    // ---- deferred-max state (log2 domain) ----
    float M2 = -1e30f, S = 0.f, U2 = 0.f, V = 0.f, BL = -1e30f;
    int BI = 0;

    const s16x8* __restrict__ wf = reinterpret_cast<const s16x8*>(wmu)
                                 + (size_t)(m * 64 + khalf * 32) * 256 + l;

    #pragma unroll 2
    for (int t = 0; t < 32; ++t) {
        const s16x8* fb = wf + t * 256;
        const s16x8 a0 = fb[0], a1 = fb[64], a2 = fb[128], a3 = fb[192];
        f32x4 acc = {0.f, 0.f, 0.f, 0.f};
        acc = __builtin_amdgcn_mfma_f32_16x16x32_bf16(a0, xf[0], acc, 0, 0, 0);
        acc = __builtin_amdgcn_mfma_f32_16x16x32_bf16(a1, xf[1], acc, 0, 0, 0);
        acc = __builtin_amdgcn_mfma_f32_16x16x32_bf16(a2, xf[2], acc, 0, 0, 0);
        acc = __builtin_amdgcn_mfma_f32_16x16x32_bf16(a3, xf[3], acc, 0, 0, 0);

        const int k0 = (khalf * 32 + t) * 16 + g * 4;   // global k of this lane's 4 logits
        const f32x4 A4 = *(const f32x4*)(As + k0);
        const f32x4 C4 = *(const f32x4*)(Cs + k0);
        const f32x4 P4 = *(const f32x4*)(Ps + k0);
        #pragma unroll
        for (int r = 0; r < 4; ++r) {
            const float L2 = fmaf(A4[r], acc[r], fmaf(-A4[r], xsh, C4[r]));
            const float diff = L2 - M2;
            if (__builtin_expect(__any(diff > DEFER_THR), 0)) {
                if (diff > DEFER_THR) {
                    const float sc = exp2f(-diff);
                    U2 = (U2 - diff * S) * sc;
                    S  = fmaf(S, sc, 1.f);
                    V  = fmaf(V, sc, P4[r]);
                    M2 = L2;
                } else {
                    const float e = exp2f(diff);
                    S += e; U2 = fmaf(e, diff, U2); V = fmaf(e, P4[r], V);
                }
            } else {
                const float e = exp2f(diff);
                S += e; U2 = fmaf(e, diff, U2); V = fmaf(e, P4[r], V);
            }
            if (L2 > BL) { BL = L2; BI = k0 + r; }
        }
    }

    // ---- intra-wave butterfly merge of 4 k-subsets ----
    #pragma unroll
    for (int off = 16; off <= 32; off <<= 1) {
        const float Mb  = __shfl_xor(M2, off, 64);
        const float Sb  = __shfl_xor(S,  off, 64);
        const float Ub  = __shfl_xor(U2, off, 64);
        const float Vb  = __shfl_xor(V,  off, 64);
        const float BLb = __shfl_xor(BL, off, 64);
        const int   BIb = __shfl_xor(BI, off, 64);
        const float Mc = fmaxf(M2, Mb);
        const float sa = exp2f(M2 - Mc), sb = exp2f(Mb - Mc);
        const float Sn = S * sa + Sb * sb;
        U2 = fmaf(M2 - Mc, S, U2) * sa + fmaf(Mb - Mc, Sb, Ub) * sb;
        V  = V * sa + Vb * sb;
        S  = Sn; M2 = Mc;
        const bool tb = (BLb > BL) || (BLb == BL && BIb < BI);
        BI = tb ? BIb : BI;
        BL = fmaxf(BL, BLb);
    }

    // ---- cross-wave k-half merge via LDS ----
    if (w >= 2 && l < 16) {
        scrM[w - 2][n] = M2;  scrS[w - 2][n] = S;
        scrU[w - 2][n] = U2;  scrV[w - 2][n] = V;
        scrBL[w - 2][n] = BL; scrBI[w - 2][n] = BI;
    }
    __syncthreads();
    if (w < 2 && l < 16) {
        const float Mb = scrM[w][n], Sb = scrS[w][n], Ub = scrU[w][n], Vb = scrV[w][n];
        const float BLb = scrBL[w][n]; const int BIb = scrBI[w][n];
        const float Mc = fmaxf(M2, Mb);
        const float sa = exp2f(M2 - Mc), sb = exp2f(Mb - Mc);
        const float Sx = S * sa + Sb * sb;
        const float Ux = fmaf(M2 - Mc, S, U2) * sa + fmaf(Mb - Mc, Sb, Ub) * sb;
        const float Vx = V * sa + Vb * sb;
        const bool tb = (BLb > BL) || (BLb == BL && BIb < BI);
        sidx[w * 16 + n] = tb ? BIb : BI;
        float kl = (LN2 * Ux - Vx) / Sx - logf(Sx);   // +lse[m] correction in vq_final
        #pragma unroll
        for (int o = 8; o >= 1; o >>= 1) kl += __shfl_xor(kl, o, 16);
        if (n == 0) wscr[w] = kl;
    }
    __syncthreads();
    if (tid == 0) partial[m * 128 + tile] = wscr[0] + wscr[1];

    // ---- sample: gather chosen mu rows coalesced -> LDS transpose -> store ----
    {
        const int p = tid >> 3, ch = tid & 7;
        const float* mrow = mus + ((size_t)m * K_CB + sidx[p]) * D_CB;
        #pragma unroll
        for (int i = 0; i < 4; ++i) {
            const float4 v = reinterpret_cast<const float4*>(mrow)[ch + i * 8];
            const int d = (ch + i * 8) * 4;
            smp[p][d + 0] = v.x; smp[p][d + 1] = v.y;
            smp[p][d + 2] = v.z; smp[p][d + 3] = v.w;
        }
    }
    __syncthreads();
    {
        const int p = tid & 31, d0 = tid >> 5;
        #pragma unroll 8
        for (int dd = d0; dd < D_CB; dd += 8)
            out[xbase + (size_t)dd * HW + p] = smp[p][dd];
    }
}

// ---- kernel 3: lse correction + final KL reduce (barrier-light) ---------------
__global__ __launch_bounds__(256) void vq_final(const float* __restrict__ logpy,
                                                const float* __restrict__ partial,
                                                float* __restrict__ out)
{
    __shared__ float lses[8];
    __shared__ float wred[4];
    const int tid = threadIdx.x;
    const int mm = tid >> 5, lane = tid & 31;

    // per-32-lane-group online logsumexp over logpy[mm][:]
    float M = -1e30f, S = 0.f;
    #pragma unroll 4
    for (int i = 0; i < 32; ++i) {
        const float v = logpy[mm * K_CB + i * 32 + lane];
        const float Mn = fmaxf(M, v);
        S = S * expf(M - Mn) + expf(v - Mn);
        M = Mn;
    }
    #pragma unroll
    for (int off = 16; off >= 1; off >>= 1) {
        const float Mb = __shfl_xor(M, off, 32);
        const float Sb = __shfl_xor(S, off, 32);
        const float Mn = fmaxf(M, Mb);
        S = S * expf(M - Mn) + Sb * expf(Mb - Mn);
        M = Mn;
    }
    if (lane == 0) lses[mm] = M + logf(S);

    float v = partial[tid] + partial[tid + 256] + partial[tid + 512] + partial[tid + 768];
    #pragma unroll
    for (int o = 32; o >= 1; o >>= 1) v += __shfl_xor(v, o, 64);
    if ((tid & 63) == 0) wred[tid >> 6] = v;
    __syncthreads();
    if (tid == 0) {
        const float ksum = wred[0] + wred[1] + wred[2] + wred[3];
        const float lsesum = lses[0] + lses[1] + lses[2] + lses[3]
                           + lses[4] + lses[5] + lses[6] + lses[7];
        out[(size_t)NB * M_CB * D_CB * HW]     = (ksum + 4096.f * lsesum) * 0.25f;
        out[(size_t)NB * M_CB * D_CB * HW + 1] = 0.f;
    }
}

extern "C" void kernel_launch(void* const* d_in, const int* in_sizes, int n_in,
                              void* d_out, int out_size, void* d_ws, size_t ws_size,
                              hipStream_t stream)
{
    const float* x      = (const float*)d_in[0];
    const float* mus    = (const float*)d_in[1];
    const float* scales = (const float*)d_in[2];
    const float* logpy  = (const float*)d_in[3];
    float* out = (float*)d_out;
    float* ws  = (float*)d_ws;

    float*  partial = ws + WS_PART;
    float*  A2l     = ws + WS_A;
    float*  c0l     = ws + WS_C0;
    ushort* wmu     = (ushort*)(ws + WS_MU_F);

    vq_convert<<<512,          256, 0, stream>>>(mus, scales, logpy, wmu, A2l, c0l);
    vq_main   <<<dim3(128, 8), 256, 0, stream>>>(x, wmu, mus, A2l, c0l, logpy, out, partial);
    vq_final  <<<1,            256, 0, stream>>>(logpy, partial, out);
}